// Round 10
// baseline (1857.334 us; speedup 1.0000x reference)
//
#include <hip/hip_runtime.h>
#include <math.h>

#define NB 64       // batch
#define NS 512      // seq len
#define ND 512      // input dim
#define NH 512      // hidden
#define NC (NS / 8) // chunks of 8 steps
#define RING 32     // h1 ring slots (4 chunks)

// 64-lane sum via DPP (VALU only). Total lands in lane 63.
__device__ __forceinline__ float dpp_sum64(float x) {
    x += __int_as_float(__builtin_amdgcn_update_dpp(0, __float_as_int(x), 0x111, 0xf, 0xf, true)); // row_shr:1
    x += __int_as_float(__builtin_amdgcn_update_dpp(0, __float_as_int(x), 0x112, 0xf, 0xf, true)); // row_shr:2
    x += __int_as_float(__builtin_amdgcn_update_dpp(0, __float_as_int(x), 0x114, 0xf, 0xf, true)); // row_shr:4
    x += __int_as_float(__builtin_amdgcn_update_dpp(0, __float_as_int(x), 0x118, 0xf, 0xf, true)); // row_shr:8
    x += __int_as_float(__builtin_amdgcn_update_dpp(0, __float_as_int(x), 0x142, 0xa, 0xf, true)); // row_bcast:15
    x += __int_as_float(__builtin_amdgcn_update_dpp(0, __float_as_int(x), 0x143, 0xc, 0xf, true)); // row_bcast:31
    return x;
}

__device__ __forceinline__ float bcast63(float x) {
    return __int_as_float(__builtin_amdgcn_readlane(__float_as_int(x), 63));
}

__device__ __forceinline__ float sigm(float x) {
    return 1.0f / (1.0f + __expf(-x));
}

__device__ __forceinline__ float tanh_fast(float x) {
    float ax = fabsf(x);
    float e = __expf(2.0f * ax);
    float r = 1.0f - 2.0f / (e + 1.0f);
    return copysignf(r, x);
}

__device__ __forceinline__ void wait_vm0() {
    asm volatile("s_waitcnt vmcnt(0)" ::: "memory");
}

__device__ __forceinline__ void spin_on(const unsigned int* p) {
    while (__hip_atomic_load(p, __ATOMIC_ACQUIRE, __HIP_MEMORY_SCOPE_AGENT) == 0) {}
}

__device__ __forceinline__ void release_flag(unsigned int* p) {
    __hip_atomic_store(p, 1u, __ATOMIC_RELEASE, __HIP_MEMORY_SCOPE_AGENT);
}

// lane l holds rows 8l..8l+7 of the weight row f (k-slice)
#define LOADW8(mat, W)                                                    \
    _Pragma("unroll")                                                     \
    for (int f = 0; f < 8; ++f) {                                         \
        *(float4*)&W[f][0] = *(const float4*)&(mat)[f * NH + 8 * l];      \
        *(float4*)&W[f][4] = *(const float4*)&(mat)[f * NH + 8 * l + 4];  \
    }

// 16 in-register reductions (8 factors x 2 matrices) over the wave's h-state
#define RED16(WA, WB, OA, OB, SV)                                         \
    _Pragma("unroll")                                                     \
    for (int f = 0; f < 8; ++f) {                                         \
        float rA = WA[f][0] * SV[0];                                      \
        float rB = WB[f][0] * SV[0];                                      \
        _Pragma("unroll")                                                 \
        for (int k = 1; k < 8; ++k) {                                     \
            rA = fmaf(WA[f][k], SV[k], rA);                               \
            rB = fmaf(WB[f][k], SV[k], rB);                               \
        }                                                                 \
        OA[f] = bcast63(dpp_sum64(rA));                                   \
        OB[f] = bcast63(dpp_sum64(rB));                                   \
    }

// 8 owned rows of gates; row 8l+jr uses factor jr. PX[0..7]=term1, PX[8..15]=term2
#define GATES8(PX, MA, MB, CWv, CDWv, CUv, CDUv, BBv, CVv, HVv)           \
    _Pragma("unroll")                                                     \
    for (int jr = 0; jr < 8; ++jr) {                                      \
        float x1 = PX[jr], x2 = PX[8 + jr];                               \
        float g0 = fmaf(CWv[0], x1, fmaf(CDWv[0], x2, fmaf(CUv[0], MA[jr], fmaf(CDUv[0], MB[jr], BBv[0][jr])))); \
        float g1 = fmaf(CWv[1], x1, fmaf(CDWv[1], x2, fmaf(CUv[1], MA[jr], fmaf(CDUv[1], MB[jr], BBv[1][jr])))); \
        float g2 = fmaf(CWv[2], x1, fmaf(CDWv[2], x2, fmaf(CUv[2], MA[jr], fmaf(CDUv[2], MB[jr], BBv[2][jr])))); \
        float g3 = fmaf(CWv[3], x1, fmaf(CDWv[3], x2, fmaf(CUv[3], MA[jr], fmaf(CDUv[3], MB[jr], BBv[3][jr])))); \
        float ig = sigm(g0), fg = sigm(g1), gg = tanh_fast(g2), og = sigm(g3); \
        CVv[jr] = fg * CVv[jr] + ig * gg;                                 \
        HVv[jr] = og * tanh_fast(CVv[jr]);                                \
    }

// ---------------------------------------------------------------------------
// Kernel A: PT[bt][0..7] = W12@x_bt, PT[bt][8..15] = dW12@x_bt
// ---------------------------------------------------------------------------
__global__ __launch_bounds__(64) void precomp_kernel(
    const float* __restrict__ x, const float* __restrict__ W12,
    const float* __restrict__ dW12, float* __restrict__ PT) {
    int bt = blockIdx.x;
    int l = threadIdx.x;
    const float4* xr = (const float4*)(x + (size_t)bt * ND);
    float4 xv0 = xr[l];
    float4 xv1 = xr[64 + l];

    float acc[16];
#pragma unroll
    for (int f = 0; f < 8; ++f) {
        const float4* w = (const float4*)(W12 + f * ND);
        float4 a = w[l], b = w[64 + l];
        float s = a.x * xv0.x;
        s = fmaf(a.y, xv0.y, s); s = fmaf(a.z, xv0.z, s); s = fmaf(a.w, xv0.w, s);
        s = fmaf(b.x, xv1.x, s); s = fmaf(b.y, xv1.y, s); s = fmaf(b.z, xv1.z, s);
        s = fmaf(b.w, xv1.w, s);
        acc[f] = s;
        const float4* dw = (const float4*)(dW12 + f * ND);
        float4 c = dw[l], d = dw[64 + l];
        float u = c.x * xv0.x;
        u = fmaf(c.y, xv0.y, u); u = fmaf(c.z, xv0.z, u); u = fmaf(c.w, xv0.w, u);
        u = fmaf(d.x, xv1.x, u); u = fmaf(d.y, xv1.y, u); u = fmaf(d.z, xv1.z, u);
        u = fmaf(d.w, xv1.w, u);
        acc[8 + f] = u;
    }
#pragma unroll
    for (int f = 0; f < 16; ++f) acc[f] = dpp_sum64(acc[f]);

    if (l == 63) {
        float4* o = (float4*)(PT + (size_t)bt * 16);
        o[0] = make_float4(acc[0], acc[1], acc[2], acc[3]);
        o[1] = make_float4(acc[4], acc[5], acc[6], acc[7]);
        o[2] = make_float4(acc[8], acc[9], acc[10], acc[11]);
        o[3] = make_float4(acc[12], acc[13], acc[14], acc[15]);
    }
}

// ---------------------------------------------------------------------------
// Kernel B: 3-stage, ONE WAVE per stage per element, no barriers, no LDS.
// Lane l owns rows 8l..8l+7; the full h-vector lives in wave registers.
//  role 0 producer : L1 recurrence; publishes h1(t+1) to ring h1buf
//  role 1 projector: m1,m2 = W22/dW22 @ h1 (no recurrence), -> mrec
//  role 2 consumer : L2 recurrence consuming mrec -> out
// Flags per 8-step chunk: flag1 prod->proj (also ring-gates prod via flag2),
// flag2 proj->cons.
// ---------------------------------------------------------------------------
__global__ __launch_bounds__(64, 1) void lstm_stage_kernel(
    const float* __restrict__ PT, const float* __restrict__ h0,
    const float* __restrict__ c0,
    const float* __restrict__ W11, const float* __restrict__ U11,
    const float* __restrict__ dW11, const float* __restrict__ dU11,
    const float* __restrict__ U12, const float* __restrict__ dU12,
    const float* __restrict__ b11, const float* __restrict__ b12,
    const float* __restrict__ W21, const float* __restrict__ U21,
    const float* __restrict__ dW21, const float* __restrict__ dU21,
    const float* __restrict__ W22, const float* __restrict__ dW22,
    const float* __restrict__ U22, const float* __restrict__ dU22,
    const float* __restrict__ b21, const float* __restrict__ b22,
    float* __restrict__ h1buf, float* __restrict__ mrec,
    unsigned int* __restrict__ flag1, unsigned int* __restrict__ flag2,
    float* __restrict__ out) {
    int role = blockIdx.x >> 6;
    int b = blockIdx.x & 63;
    int l = threadIdx.x;

    float* hn = out + (size_t)NB * NS * NH;
    float* cn = hn + (size_t)2 * NB * NH;

    if (role == 0) {
        // ======================= PRODUCER (layer 1) =======================
        float wa[8][8], wb[8][8];
        LOADW8(U12, wa)
        LOADW8(dU12, wb)
        float cw[4], cdw[4], cu[4], cdu[4], bbv[4][8];
#pragma unroll
        for (int q = 0; q < 4; ++q) {
            cw[q] = W11[q * 64 + l]; cdw[q] = dW11[q * 64 + l];
            cu[q] = U11[q * 64 + l]; cdu[q] = dU11[q * 64 + l];
            float4 a0 = *(const float4*)&b11[q * NH + 8 * l];
            float4 a1 = *(const float4*)&b11[q * NH + 8 * l + 4];
            float4 c0v = *(const float4*)&b12[q * NH + 8 * l];
            float4 c1v = *(const float4*)&b12[q * NH + 8 * l + 4];
            bbv[q][0] = a0.x + c0v.x; bbv[q][1] = a0.y + c0v.y;
            bbv[q][2] = a0.z + c0v.z; bbv[q][3] = a0.w + c0v.w;
            bbv[q][4] = a1.x + c1v.x; bbv[q][5] = a1.y + c1v.y;
            bbv[q][6] = a1.z + c1v.z; bbv[q][7] = a1.w + c1v.w;
        }
        float hv[8], cv[8];
        {
            float4 h0a = *(const float4*)&h0[(size_t)b * NH + 8 * l];
            float4 h0b = *(const float4*)&h0[(size_t)b * NH + 8 * l + 4];
            float4 c0a = *(const float4*)&c0[(size_t)b * NH + 8 * l];
            float4 c0b = *(const float4*)&c0[(size_t)b * NH + 8 * l + 4];
            hv[0] = h0a.x; hv[1] = h0a.y; hv[2] = h0a.z; hv[3] = h0a.w;
            hv[4] = h0b.x; hv[5] = h0b.y; hv[6] = h0b.z; hv[7] = h0b.w;
            cv[0] = c0a.x; cv[1] = c0a.y; cv[2] = c0a.z; cv[3] = c0a.w;
            cv[4] = c0b.x; cv[5] = c0b.y; cv[6] = c0b.z; cv[7] = c0b.w;
        }
        float Pc[16], Pn[16], m3[8], m4[8];
        {
            const float4* pp = (const float4*)(PT + (size_t)b * NS * 16);
            *(float4*)&Pc[0] = pp[0]; *(float4*)&Pc[4] = pp[1];
            *(float4*)&Pc[8] = pp[2]; *(float4*)&Pc[12] = pp[3];
        }
        // prologue: h1(1) from h1(0), P(0)
        RED16(wa, wb, m3, m4, hv)
        GATES8(Pc, m3, m4, cw, cdw, cu, cdu, bbv, cv, hv)
        {
            const float4* pp = (const float4*)(PT + ((size_t)b * NS + 1) * 16);
            *(float4*)&Pn[0] = pp[0]; *(float4*)&Pn[4] = pp[1];
            *(float4*)&Pn[8] = pp[2]; *(float4*)&Pn[12] = pp[3];
        }
        unsigned int* f1 = flag1 + b * NC;
        const unsigned int* f2 = flag2 + b * NC;

        for (int t = 0; t < NS; ++t) {
            // ring gate: chunk c reuses chunk c-4's slots
            if ((t & 7) == 0 && t >= RING) spin_on(&f2[(t >> 3) - 4]);
            // publish h1(t+1) (current hv) to ring slot t&31
            float* hb = h1buf + ((size_t)b * RING + (t & (RING - 1))) * NH + 8 * l;
            *(float4*)&hb[0] = make_float4(hv[0], hv[1], hv[2], hv[3]);
            *(float4*)&hb[4] = make_float4(hv[4], hv[5], hv[6], hv[7]);
            if (t < NS - 1) {
#pragma unroll
                for (int k = 0; k < 16; ++k) Pc[k] = Pn[k];
                int tn = (t + 2 < NS) ? t + 2 : NS - 1;
                const float4* pp = (const float4*)(PT + ((size_t)b * NS + tn) * 16);
                *(float4*)&Pn[0] = pp[0]; *(float4*)&Pn[4] = pp[1];
                *(float4*)&Pn[8] = pp[2]; *(float4*)&Pn[12] = pp[3];
                RED16(wa, wb, m3, m4, hv)
                GATES8(Pc, m3, m4, cw, cdw, cu, cdu, bbv, cv, hv)
            }
            if ((t & 7) == 7) {
                wait_vm0();
                if (l == 0) release_flag(&f1[t >> 3]);
            }
        }
        *(float4*)&hn[(size_t)b * NH + 8 * l] = make_float4(hv[0], hv[1], hv[2], hv[3]);
        *(float4*)&hn[(size_t)b * NH + 8 * l + 4] = make_float4(hv[4], hv[5], hv[6], hv[7]);
        *(float4*)&cn[(size_t)b * NH + 8 * l] = make_float4(cv[0], cv[1], cv[2], cv[3]);
        *(float4*)&cn[(size_t)b * NH + 8 * l + 4] = make_float4(cv[4], cv[5], cv[6], cv[7]);
    } else if (role == 1) {
        // ======================= PROJECTOR (W22/dW22 @ h1) ================
        float wa[8][8], wb[8][8];
        LOADW8(W22, wa)
        LOADW8(dW22, wb)
        const unsigned int* f1 = flag1 + b * NC;
        unsigned int* f2 = flag2 + b * NC;

        for (int c = 0; c < NC; ++c) {
            spin_on(&f1[c]);
            float ha[8];
            {
                const float* hp = h1buf + ((size_t)b * RING + ((8 * c) & (RING - 1))) * NH + 8 * l;
                float4 v0 = *(const float4*)&hp[0];
                float4 v1 = *(const float4*)&hp[4];
                ha[0] = v0.x; ha[1] = v0.y; ha[2] = v0.z; ha[3] = v0.w;
                ha[4] = v1.x; ha[5] = v1.y; ha[6] = v1.z; ha[7] = v1.w;
            }
#pragma unroll
            for (int j = 0; j < 8; ++j) {
                int t = 8 * c + j;
                float hb2[8];
                if (j < 7) {
                    const float* hp = h1buf + ((size_t)b * RING + ((t + 1) & (RING - 1))) * NH + 8 * l;
                    float4 v0 = *(const float4*)&hp[0];
                    float4 v1 = *(const float4*)&hp[4];
                    hb2[0] = v0.x; hb2[1] = v0.y; hb2[2] = v0.z; hb2[3] = v0.w;
                    hb2[4] = v1.x; hb2[5] = v1.y; hb2[6] = v1.z; hb2[7] = v1.w;
                }
                float r1[8], r2[8];
#pragma unroll
                for (int f = 0; f < 8; ++f) {
                    float rA = wa[f][0] * ha[0];
                    float rB = wb[f][0] * ha[0];
#pragma unroll
                    for (int k = 1; k < 8; ++k) {
                        rA = fmaf(wa[f][k], ha[k], rA);
                        rB = fmaf(wb[f][k], ha[k], rB);
                    }
                    r1[f] = dpp_sum64(rA);
                    r2[f] = dpp_sum64(rB);
                }
                if (l == 63) {
                    float4* mr = (float4*)(mrec + ((size_t)b * NS + t) * 16);
                    mr[0] = make_float4(r1[0], r1[1], r1[2], r1[3]);
                    mr[1] = make_float4(r1[4], r1[5], r1[6], r1[7]);
                    mr[2] = make_float4(r2[0], r2[1], r2[2], r2[3]);
                    mr[3] = make_float4(r2[4], r2[5], r2[6], r2[7]);
                }
                if (j < 7) {
#pragma unroll
                    for (int k = 0; k < 8; ++k) ha[k] = hb2[k];
                }
            }
            wait_vm0();
            if (l == 0) release_flag(&f2[c]);
        }
    } else {
        // ======================= CONSUMER (layer 2) =======================
        float wa[8][8], wb[8][8];
        LOADW8(U22, wa)
        LOADW8(dU22, wb)
        float cw[4], cdw[4], cu[4], cdu[4], bbv[4][8];
#pragma unroll
        for (int q = 0; q < 4; ++q) {
            cw[q] = W21[q * 64 + l]; cdw[q] = dW21[q * 64 + l];
            cu[q] = U21[q * 64 + l]; cdu[q] = dU21[q * 64 + l];
            float4 a0 = *(const float4*)&b21[q * NH + 8 * l];
            float4 a1 = *(const float4*)&b21[q * NH + 8 * l + 4];
            float4 c0v = *(const float4*)&b22[q * NH + 8 * l];
            float4 c1v = *(const float4*)&b22[q * NH + 8 * l + 4];
            bbv[q][0] = a0.x + c0v.x; bbv[q][1] = a0.y + c0v.y;
            bbv[q][2] = a0.z + c0v.z; bbv[q][3] = a0.w + c0v.w;
            bbv[q][4] = a1.x + c1v.x; bbv[q][5] = a1.y + c1v.y;
            bbv[q][6] = a1.z + c1v.z; bbv[q][7] = a1.w + c1v.w;
        }
        float hv[8], cv[8];
        {
            const float* hp = h0 + (size_t)NB * NH + (size_t)b * NH + 8 * l;
            const float* cp = c0 + (size_t)NB * NH + (size_t)b * NH + 8 * l;
            float4 h0a = *(const float4*)&hp[0], h0b = *(const float4*)&hp[4];
            float4 c0a = *(const float4*)&cp[0], c0b = *(const float4*)&cp[4];
            hv[0] = h0a.x; hv[1] = h0a.y; hv[2] = h0a.z; hv[3] = h0a.w;
            hv[4] = h0b.x; hv[5] = h0b.y; hv[6] = h0b.z; hv[7] = h0b.w;
            cv[0] = c0a.x; cv[1] = c0a.y; cv[2] = c0a.z; cv[3] = c0a.w;
            cv[4] = c0b.x; cv[5] = c0b.y; cv[6] = c0b.z; cv[7] = c0b.w;
        }
        const unsigned int* f2 = flag2 + b * NC;
        float Ma[16], Mn[16], m5[8], m6[8];

        for (int c = 0; c < NC; ++c) {
            spin_on(&f2[c]);
            {
                const float4* mr = (const float4*)(mrec + ((size_t)b * NS + 8 * c) * 16);
                *(float4*)&Ma[0] = mr[0]; *(float4*)&Ma[4] = mr[1];
                *(float4*)&Ma[8] = mr[2]; *(float4*)&Ma[12] = mr[3];
            }
#pragma unroll
            for (int j = 0; j < 8; ++j) {
                int t = 8 * c + j;
                if (j < 7) {
                    const float4* mr = (const float4*)(mrec + ((size_t)b * NS + t + 1) * 16);
                    *(float4*)&Mn[0] = mr[0]; *(float4*)&Mn[4] = mr[1];
                    *(float4*)&Mn[8] = mr[2]; *(float4*)&Mn[12] = mr[3];
                }
                RED16(wa, wb, m5, m6, hv)
                GATES8(Ma, m5, m6, cw, cdw, cu, cdu, bbv, cv, hv)
                float* ob = out + ((size_t)b * NS + t) * NH + 8 * l;
                *(float4*)&ob[0] = make_float4(hv[0], hv[1], hv[2], hv[3]);
                *(float4*)&ob[4] = make_float4(hv[4], hv[5], hv[6], hv[7]);
                if (j < 7) {
#pragma unroll
                    for (int k = 0; k < 16; ++k) Ma[k] = Mn[k];
                }
            }
        }
        float* hnp = hn + (size_t)NB * NH + (size_t)b * NH + 8 * l;
        float* cnp = cn + (size_t)NB * NH + (size_t)b * NH + 8 * l;
        *(float4*)&hnp[0] = make_float4(hv[0], hv[1], hv[2], hv[3]);
        *(float4*)&hnp[4] = make_float4(hv[4], hv[5], hv[6], hv[7]);
        *(float4*)&cnp[0] = make_float4(cv[0], cv[1], cv[2], cv[3]);
        *(float4*)&cnp[4] = make_float4(cv[4], cv[5], cv[6], cv[7]);
    }
}

extern "C" void kernel_launch(void* const* d_in, const int* in_sizes, int n_in,
                              void* d_out, int out_size, void* d_ws, size_t ws_size,
                              hipStream_t stream) {
    const float* x = (const float*)d_in[0];
    const float* h0 = (const float*)d_in[1];
    const float* c0 = (const float*)d_in[2];
    const float* W11 = (const float*)d_in[3];
    const float* W12 = (const float*)d_in[4];
    const float* U11 = (const float*)d_in[5];
    const float* U12 = (const float*)d_in[6];
    const float* dW11 = (const float*)d_in[7];
    const float* dW12 = (const float*)d_in[8];
    const float* dU11 = (const float*)d_in[9];
    const float* dU12 = (const float*)d_in[10];
    const float* b11 = (const float*)d_in[11];
    const float* b12 = (const float*)d_in[12];
    const float* W21 = (const float*)d_in[13];
    const float* W22 = (const float*)d_in[14];
    const float* U21 = (const float*)d_in[15];
    const float* U22 = (const float*)d_in[16];
    const float* dW21 = (const float*)d_in[17];
    const float* dW22 = (const float*)d_in[18];
    const float* dU21 = (const float*)d_in[19];
    const float* dU22 = (const float*)d_in[20];
    const float* b21 = (const float*)d_in[21];
    const float* b22 = (const float*)d_in[22];

    char* ws = (char*)d_ws;
    float* PT = (float*)ws;                                        // 2 MB
    float* mrec = (float*)(ws + (size_t)2 * 1024 * 1024);          // 2 MB
    float* h1buf = (float*)(ws + (size_t)4 * 1024 * 1024);         // 4 MB ring
    unsigned int* flag1 = (unsigned int*)(ws + (size_t)8 * 1024 * 1024);   // 16 KB
    unsigned int* flag2 = flag1 + NB * NC;                                  // 16 KB
    float* out = (float*)d_out;

    hipMemsetAsync(flag1, 0, 2 * NB * NC * sizeof(unsigned int), stream);
    hipLaunchKernelGGL(precomp_kernel, dim3(NB * NS), dim3(64), 0, stream,
                       x, W12, dW12, PT);
    hipLaunchKernelGGL(lstm_stage_kernel, dim3(3 * NB), dim3(64), 0, stream,
                       PT, h0, c0,
                       W11, U11, dW11, dU11, U12, dU12, b11, b12,
                       W21, U21, dW21, dU21, W22, dW22, U22, dU22, b21, b22,
                       h1buf, mrec, flag1, flag2, out);
}

// Round 11
// 634.979 us; speedup vs baseline: 2.9250x; 2.9250x over previous
//
#include <hip/hip_runtime.h>
#include <math.h>

#define NB 64       // batch
#define NS 512      // seq len
#define ND 512      // input dim
#define NH 512      // hidden
#define NC (NS / 8) // 8-step chunks

// 64-lane sum via DPP (VALU only). Total lands in lane 63.
__device__ __forceinline__ float dpp_sum64(float x) {
    x += __int_as_float(__builtin_amdgcn_update_dpp(0, __float_as_int(x), 0x111, 0xf, 0xf, true)); // row_shr:1
    x += __int_as_float(__builtin_amdgcn_update_dpp(0, __float_as_int(x), 0x112, 0xf, 0xf, true)); // row_shr:2
    x += __int_as_float(__builtin_amdgcn_update_dpp(0, __float_as_int(x), 0x114, 0xf, 0xf, true)); // row_shr:4
    x += __int_as_float(__builtin_amdgcn_update_dpp(0, __float_as_int(x), 0x118, 0xf, 0xf, true)); // row_shr:8
    x += __int_as_float(__builtin_amdgcn_update_dpp(0, __float_as_int(x), 0x142, 0xa, 0xf, true)); // row_bcast:15
    x += __int_as_float(__builtin_amdgcn_update_dpp(0, __float_as_int(x), 0x143, 0xc, 0xf, true)); // row_bcast:31
    return x;
}

__device__ __forceinline__ float rcp_fast(float x) { return __builtin_amdgcn_rcpf(x); }
__device__ __forceinline__ float exp2_fast(float x) {
    float r;
    asm("v_exp_f32 %0, %1" : "=v"(r) : "v"(x));
    return r;
}
// gate inputs are PRE-SCALED by -log2e (sigmoid gates) / +2log2e (tanh gate):
//   sigm(raw) = 1/(1+2^(-L*raw)),  tanh(raw) = 1 - 2/(1+2^(2L*raw))
#define L2E 1.4426950408889634f

__device__ __forceinline__ void wg_barrier() {
    asm volatile("s_waitcnt lgkmcnt(0)\n\ts_barrier" ::: "memory");
}
__device__ __forceinline__ void wait_vm0() {
    asm volatile("s_waitcnt vmcnt(0)" ::: "memory");
}
__device__ __forceinline__ void spin_on(const unsigned int* p) {
    while (__hip_atomic_load(p, __ATOMIC_ACQUIRE, __HIP_MEMORY_SCOPE_AGENT) == 0) {}
}
__device__ __forceinline__ void release_flag(unsigned int* p) {
    __hip_atomic_store(p, 1u, __ATOMIC_RELEASE, __HIP_MEMORY_SCOPE_AGENT);
}

// load 8-float k-slice (cols 8l..8l+7) of factor row f
#define LW8(mat, f, arr)                                                      \
    {                                                                         \
        *(float4*)&arr[0] = *(const float4*)&(mat)[(f) * NH + 8 * l];         \
        *(float4*)&arr[4] = *(const float4*)&(mat)[(f) * NH + 8 * l + 4];     \
    }

// 4 dots over the in-register h replica (8 elems/lane), DPP-reduced
#define DOTS4(WA, WB, WC, WD, r0, r1, r2, r3)                                 \
    {                                                                         \
        r0 = WA[0] * hv[0]; r1 = WB[0] * hv[0];                               \
        r2 = WC[0] * hv[0]; r3 = WD[0] * hv[0];                               \
        _Pragma("unroll")                                                     \
        for (int k = 1; k < 8; ++k) {                                         \
            r0 = fmaf(WA[k], hv[k], r0); r1 = fmaf(WB[k], hv[k], r1);         \
            r2 = fmaf(WC[k], hv[k], r2); r3 = fmaf(WD[k], hv[k], r3);         \
        }                                                                     \
        r0 = dpp_sum64(r0); r1 = dpp_sum64(r1);                               \
        r2 = dpp_sum64(r2); r3 = dpp_sum64(r3);                               \
    }

// gates for the thread's 8 rows (row 8l+j uses factor j); updates hv/cv
#define GATE8(PXa, PXb, M3a, M4a)                                             \
    _Pragma("unroll")                                                         \
    for (int j = 0; j < 8; ++j) {                                             \
        float g0 = fmaf(cw[0], PXa[j], fmaf(cdw[0], PXb[j], fmaf(cu[0], M3a[j], fmaf(cdu[0], M4a[j], bb0[j])))); \
        float g1 = fmaf(cw[1], PXa[j], fmaf(cdw[1], PXb[j], fmaf(cu[1], M3a[j], fmaf(cdu[1], M4a[j], bb1[j])))); \
        float g2 = fmaf(cw[2], PXa[j], fmaf(cdw[2], PXb[j], fmaf(cu[2], M3a[j], fmaf(cdu[2], M4a[j], bb2[j])))); \
        float g3 = fmaf(cw[3], PXa[j], fmaf(cdw[3], PXb[j], fmaf(cu[3], M3a[j], fmaf(cdu[3], M4a[j], bb3[j])))); \
        float ig = rcp_fast(1.0f + exp2_fast(g0));                            \
        float fg = rcp_fast(1.0f + exp2_fast(g1));                            \
        float gg = fmaf(-2.0f, rcp_fast(1.0f + exp2_fast(g2)), 1.0f);         \
        float og = rcp_fast(1.0f + exp2_fast(g3));                            \
        cv[j] = fmaf(fg, cv[j], ig * gg);                                     \
        float th = fmaf(-2.0f, rcp_fast(1.0f + exp2_fast(cv[j] * (2.0f * L2E))), 1.0f); \
        hv[j] = og * th;                                                      \
    }

#define UNPACK8(arr, v0, v1)                                                  \
    arr[0] = v0.x; arr[1] = v0.y; arr[2] = v0.z; arr[3] = v0.w;               \
    arr[4] = v1.x; arr[5] = v1.y; arr[6] = v1.z; arr[7] = v1.w;

// ---------------------------------------------------------------------------
// Kernel A: PT[bt][0..7] = W12@x_bt, PT[bt][8..15] = dW12@x_bt  (RAW values)
// ---------------------------------------------------------------------------
__global__ __launch_bounds__(64) void precomp_kernel(
    const float* __restrict__ x, const float* __restrict__ W12,
    const float* __restrict__ dW12, float* __restrict__ PT) {
    int bt = blockIdx.x;
    int l = threadIdx.x;
    const float4* xr = (const float4*)(x + (size_t)bt * ND);
    float4 xv0 = xr[l];
    float4 xv1 = xr[64 + l];

    float acc[16];
#pragma unroll
    for (int f = 0; f < 8; ++f) {
        const float4* w = (const float4*)(W12 + f * ND);
        float4 a = w[l], b = w[64 + l];
        float s = a.x * xv0.x;
        s = fmaf(a.y, xv0.y, s); s = fmaf(a.z, xv0.z, s); s = fmaf(a.w, xv0.w, s);
        s = fmaf(b.x, xv1.x, s); s = fmaf(b.y, xv1.y, s); s = fmaf(b.z, xv1.z, s);
        s = fmaf(b.w, xv1.w, s);
        acc[f] = s;
        const float4* dw = (const float4*)(dW12 + f * ND);
        float4 c = dw[l], d = dw[64 + l];
        float u = c.x * xv0.x;
        u = fmaf(c.y, xv0.y, u); u = fmaf(c.z, xv0.z, u); u = fmaf(c.w, xv0.w, u);
        u = fmaf(d.x, xv1.x, u); u = fmaf(d.y, xv1.y, u); u = fmaf(d.z, xv1.z, u);
        u = fmaf(d.w, xv1.w, u);
        acc[8 + f] = u;
    }
#pragma unroll
    for (int f = 0; f < 16; ++f) acc[f] = dpp_sum64(acc[f]);

    if (l == 63) {
        float4* o = (float4*)(PT + (size_t)bt * 16);
        o[0] = make_float4(acc[0], acc[1], acc[2], acc[3]);
        o[1] = make_float4(acc[4], acc[5], acc[6], acc[7]);
        o[2] = make_float4(acc[8], acc[9], acc[10], acc[11]);
        o[3] = make_float4(acc[12], acc[13], acc[14], acc[15]);
    }
}

// ---------------------------------------------------------------------------
// Kernel B: 2-stage pipeline, 4-wave blocks, h/c REPLICATED in registers.
// 128 blocks x 256 threads. Thread (any wave) owns rows 8l..8l+7 of its
// element's layer state; all 4 waves hold identical replicas (identical
// gate computation keeps them in sync). Wave w computes dot-product factors
// {2w, 2w+1}; only the 16-32 reduced values cross waves via a tiny
// double-buffered LDS buffer -> ONE barrier per step.
//  role 0: layer-1 recurrence + W22/dW22 projections -> mrec + chunk flags
//  role 1: layer-2 recurrence; wave1 stages mrec chunks (store-free wave);
//          wave0 writes out (fire-and-forget).
// ---------------------------------------------------------------------------
__global__ __launch_bounds__(256, 1) void lstm_rep_kernel(
    const float* __restrict__ PT, const float* __restrict__ h0,
    const float* __restrict__ c0,
    const float* __restrict__ W11, const float* __restrict__ U11,
    const float* __restrict__ dW11, const float* __restrict__ dU11,
    const float* __restrict__ U12, const float* __restrict__ dU12,
    const float* __restrict__ b11, const float* __restrict__ b12,
    const float* __restrict__ W21, const float* __restrict__ U21,
    const float* __restrict__ dW21, const float* __restrict__ dU21,
    const float* __restrict__ W22, const float* __restrict__ dW22,
    const float* __restrict__ U22, const float* __restrict__ dU22,
    const float* __restrict__ b21, const float* __restrict__ b22,
    float* __restrict__ mrec, unsigned int* __restrict__ flagb,
    float* __restrict__ out) {
    int role = blockIdx.x >> 6;
    int b = blockIdx.x & 63;
    int tid = threadIdx.x;
    int wv = tid >> 6;          // wave -> factor pair {2wv, 2wv+1}
    int l = tid & 63;
    int f0 = 2 * wv;

    __shared__ float lds_P[NS * 16];   // producer: full P slice (32 KB)
    __shared__ float lm[2][32];        // m exchange, double-buffered
    __shared__ float lmr[2][128];      // consumer: mrec chunk, double-buffered

    float* hn = out + (size_t)NB * NS * NH;
    float* cn = hn + (size_t)2 * NB * NH;

    // gate coefficient scales: gates 0,1,3 sigmoid (-log2e), gate 2 tanh (+2log2e)
    const float SQ0 = -L2E, SQ1 = -L2E, SQ2 = 2.0f * L2E, SQ3 = -L2E;

    if (role == 0) {
        // ======================= PRODUCER (layer 1) =======================
        {   // stage P slice into LDS (startup only)
            const float4* src = (const float4*)(PT + (size_t)b * NS * 16);
            float4* dst = (float4*)lds_P;
#pragma unroll
            for (int i = 0; i < 8; ++i) dst[tid + i * 256] = src[tid + i * 256];
        }
        float u0[8], u1[8], du0[8], du1[8], w0[8], w1[8], dw0[8], dw1[8];
        LW8(U12, f0, u0)  LW8(U12, f0 + 1, u1)
        LW8(dU12, f0, du0) LW8(dU12, f0 + 1, du1)
        LW8(W22, f0, w0)  LW8(W22, f0 + 1, w1)
        LW8(dW22, f0, dw0) LW8(dW22, f0 + 1, dw1)

        float cw[4], cdw[4], cu[4], cdu[4], bb0[8], bb1[8], bb2[8], bb3[8];
        {
            cw[0] = W11[l] * SQ0;        cw[1] = W11[64 + l] * SQ1;
            cw[2] = W11[128 + l] * SQ2;  cw[3] = W11[192 + l] * SQ3;
            cdw[0] = dW11[l] * SQ0;      cdw[1] = dW11[64 + l] * SQ1;
            cdw[2] = dW11[128 + l] * SQ2; cdw[3] = dW11[192 + l] * SQ3;
            cu[0] = U11[l] * SQ0;        cu[1] = U11[64 + l] * SQ1;
            cu[2] = U11[128 + l] * SQ2;  cu[3] = U11[192 + l] * SQ3;
            cdu[0] = dU11[l] * SQ0;      cdu[1] = dU11[64 + l] * SQ1;
            cdu[2] = dU11[128 + l] * SQ2; cdu[3] = dU11[192 + l] * SQ3;
#pragma unroll
            for (int j = 0; j < 8; ++j) {
                bb0[j] = (b11[8 * l + j] + b12[8 * l + j]) * SQ0;
                bb1[j] = (b11[NH + 8 * l + j] + b12[NH + 8 * l + j]) * SQ1;
                bb2[j] = (b11[2 * NH + 8 * l + j] + b12[2 * NH + 8 * l + j]) * SQ2;
                bb3[j] = (b11[3 * NH + 8 * l + j] + b12[3 * NH + 8 * l + j]) * SQ3;
            }
        }
        float hv[8], cv[8];
        {
            float4 a = *(const float4*)&h0[(size_t)b * NH + 8 * l];
            float4 bq = *(const float4*)&h0[(size_t)b * NH + 8 * l + 4];
            UNPACK8(hv, a, bq)
            float4 c = *(const float4*)&c0[(size_t)b * NH + 8 * l];
            float4 d = *(const float4*)&c0[(size_t)b * NH + 8 * l + 4];
            UNPACK8(cv, c, d)
        }
        wg_barrier();  // P staging visible

        // ---- prologue: L1 step 0 (h1(0) -> h1(1)) using P(0) ----
        {
            float r0, r1, r2, r3;
            DOTS4(u0, u1, du0, du1, r0, r1, r2, r3)
            if (l == 63) {
                *(float2*)&lm[1][f0] = make_float2(r0, r1);
                *(float2*)&lm[1][8 + f0] = make_float2(r2, r3);
            }
            wg_barrier();
            float m3[8], m4[8], px[8], py[8];
            {
                float4 a0 = *(const float4*)&lm[1][0], a1 = *(const float4*)&lm[1][4];
                float4 b0 = *(const float4*)&lm[1][8], b1 = *(const float4*)&lm[1][12];
                UNPACK8(m3, a0, a1) UNPACK8(m4, b0, b1)
                float4 p0 = *(const float4*)&lds_P[0], p1 = *(const float4*)&lds_P[4];
                float4 p2 = *(const float4*)&lds_P[8], p3 = *(const float4*)&lds_P[12];
                UNPACK8(px, p0, p1) UNPACK8(py, p2, p3)
            }
            GATE8(px, py, m3, m4)
        }

        unsigned int* fb = flagb + b * NC;
        for (int t = 0; t < NS; ++t) {
            const int buf = t & 1;
            // 8 dots on hv = h1(t+1): U12/dU12 (for gates t+1), W22/dW22 (mrec[t])
            float rU0, rU1, rD0, rD1, rW0, rW1, rV0, rV1;
            DOTS4(u0, u1, du0, du1, rU0, rU1, rD0, rD1)
            DOTS4(w0, w1, dw0, dw1, rW0, rW1, rV0, rV1)
            if (l == 63) {
                *(float2*)&lm[buf][f0] = make_float2(rU0, rU1);
                *(float2*)&lm[buf][8 + f0] = make_float2(rD0, rD1);
                *(float2*)&lm[buf][16 + f0] = make_float2(rW0, rW1);
                *(float2*)&lm[buf][24 + f0] = make_float2(rV0, rV1);
            }
            wg_barrier();
            // wave0 lanes 0..3 store mrec[t] (16 floats, contiguous 64B)
            if (wv == 0 && l < 4) {
                float4 mw = *(const float4*)&lm[buf][16 + 4 * l];
                *(float4*)&mrec[((size_t)b * NS + t) * 16 + 4 * l] = mw;
            }
            if (t < NS - 1) {
                float m3[8], m4[8], px[8], py[8];
                {
                    float4 a0 = *(const float4*)&lm[buf][0], a1 = *(const float4*)&lm[buf][4];
                    float4 b0 = *(const float4*)&lm[buf][8], b1 = *(const float4*)&lm[buf][12];
                    UNPACK8(m3, a0, a1) UNPACK8(m4, b0, b1)
                    const float* Pp = &lds_P[(t + 1) * 16];
                    float4 p0 = *(const float4*)&Pp[0], p1 = *(const float4*)&Pp[4];
                    float4 p2 = *(const float4*)&Pp[8], p3 = *(const float4*)&Pp[12];
                    UNPACK8(px, p0, p1) UNPACK8(py, p2, p3)
                }
                GATE8(px, py, m3, m4)
            }
            if ((t & 7) == 7 && wv == 0) {
                wait_vm0();
                if (l == 0) release_flag(&fb[t >> 3]);
            }
        }
        if (wv == 0) {
            *(float4*)&hn[(size_t)b * NH + 8 * l] = make_float4(hv[0], hv[1], hv[2], hv[3]);
            *(float4*)&hn[(size_t)b * NH + 8 * l + 4] = make_float4(hv[4], hv[5], hv[6], hv[7]);
            *(float4*)&cn[(size_t)b * NH + 8 * l] = make_float4(cv[0], cv[1], cv[2], cv[3]);
            *(float4*)&cn[(size_t)b * NH + 8 * l + 4] = make_float4(cv[4], cv[5], cv[6], cv[7]);
        }
    } else {
        // ======================= CONSUMER (layer 2) =======================
        float u0[8], u1[8], du0[8], du1[8];
        LW8(U22, f0, u0)  LW8(U22, f0 + 1, u1)
        LW8(dU22, f0, du0) LW8(dU22, f0 + 1, du1)

        float cw[4], cdw[4], cu[4], cdu[4], bb0[8], bb1[8], bb2[8], bb3[8];
        {
            cw[0] = W21[l] * SQ0;        cw[1] = W21[64 + l] * SQ1;
            cw[2] = W21[128 + l] * SQ2;  cw[3] = W21[192 + l] * SQ3;
            cdw[0] = dW21[l] * SQ0;      cdw[1] = dW21[64 + l] * SQ1;
            cdw[2] = dW21[128 + l] * SQ2; cdw[3] = dW21[192 + l] * SQ3;
            cu[0] = U21[l] * SQ0;        cu[1] = U21[64 + l] * SQ1;
            cu[2] = U21[128 + l] * SQ2;  cu[3] = U21[192 + l] * SQ3;
            cdu[0] = dU21[l] * SQ0;      cdu[1] = dU21[64 + l] * SQ1;
            cdu[2] = dU21[128 + l] * SQ2; cdu[3] = dU21[192 + l] * SQ3;
#pragma unroll
            for (int j = 0; j < 8; ++j) {
                bb0[j] = (b21[8 * l + j] + b22[8 * l + j]) * SQ0;
                bb1[j] = (b21[NH + 8 * l + j] + b22[NH + 8 * l + j]) * SQ1;
                bb2[j] = (b21[2 * NH + 8 * l + j] + b22[2 * NH + 8 * l + j]) * SQ2;
                bb3[j] = (b21[3 * NH + 8 * l + j] + b22[3 * NH + 8 * l + j]) * SQ3;
            }
        }
        float hv[8], cv[8];
        {
            const float* hp = h0 + (size_t)NB * NH + (size_t)b * NH + 8 * l;
            const float* cp = c0 + (size_t)NB * NH + (size_t)b * NH + 8 * l;
            float4 a = *(const float4*)&hp[0], bq = *(const float4*)&hp[4];
            UNPACK8(hv, a, bq)
            float4 c = *(const float4*)&cp[0], d = *(const float4*)&cp[4];
            UNPACK8(cv, c, d)
        }

        const unsigned int* fb = flagb + b * NC;
        for (int c = 0; c < NC; ++c) {
            const int cb = c & 1;
            if (wv == 1) {  // store-free wave stages the mrec chunk
                spin_on(&fb[c]);
                if (l < 32) {
                    float4 v = *(const float4*)&mrec[((size_t)b * NS + c * 8) * 16 + 4 * l];
                    *(float4*)&lmr[cb][4 * l] = v;
                }
            }
            wg_barrier();  // chunk data visible to all waves
#pragma unroll
            for (int j = 0; j < 8; ++j) {
                int t = c * 8 + j;
                const int buf = t & 1;
                float r0, r1, r2, r3;
                DOTS4(u0, u1, du0, du1, r0, r1, r2, r3)
                if (l == 63) {
                    *(float2*)&lm[buf][f0] = make_float2(r0, r1);
                    *(float2*)&lm[buf][8 + f0] = make_float2(r2, r3);
                }
                wg_barrier();
                float m5[8], m6[8], m1[8], m2[8];
                {
                    float4 a0 = *(const float4*)&lm[buf][0], a1 = *(const float4*)&lm[buf][4];
                    float4 b0 = *(const float4*)&lm[buf][8], b1 = *(const float4*)&lm[buf][12];
                    UNPACK8(m5, a0, a1) UNPACK8(m6, b0, b1)
                    const float* mp = &lmr[cb][j * 16];
                    float4 q0 = *(const float4*)&mp[0], q1 = *(const float4*)&mp[4];
                    float4 q2 = *(const float4*)&mp[8], q3 = *(const float4*)&mp[12];
                    UNPACK8(m1, q0, q1) UNPACK8(m2, q2, q3)
                }
                GATE8(m1, m2, m5, m6)
                if (wv == 0) {  // out[t] = h2(t+1), fire-and-forget
                    float* ob = out + ((size_t)b * NS + t) * NH + 8 * l;
                    *(float4*)&ob[0] = make_float4(hv[0], hv[1], hv[2], hv[3]);
                    *(float4*)&ob[4] = make_float4(hv[4], hv[5], hv[6], hv[7]);
                }
            }
        }
        if (wv == 0) {
            float* hnp = hn + (size_t)NB * NH + (size_t)b * NH + 8 * l;
            float* cnp = cn + (size_t)NB * NH + (size_t)b * NH + 8 * l;
            *(float4*)&hnp[0] = make_float4(hv[0], hv[1], hv[2], hv[3]);
            *(float4*)&hnp[4] = make_float4(hv[4], hv[5], hv[6], hv[7]);
            *(float4*)&cnp[0] = make_float4(cv[0], cv[1], cv[2], cv[3]);
            *(float4*)&cnp[4] = make_float4(cv[4], cv[5], cv[6], cv[7]);
        }
    }
}

extern "C" void kernel_launch(void* const* d_in, const int* in_sizes, int n_in,
                              void* d_out, int out_size, void* d_ws, size_t ws_size,
                              hipStream_t stream) {
    const float* x = (const float*)d_in[0];
    const float* h0 = (const float*)d_in[1];
    const float* c0 = (const float*)d_in[2];
    const float* W11 = (const float*)d_in[3];
    const float* W12 = (const float*)d_in[4];
    const float* U11 = (const float*)d_in[5];
    const float* U12 = (const float*)d_in[6];
    const float* dW11 = (const float*)d_in[7];
    const float* dW12 = (const float*)d_in[8];
    const float* dU11 = (const float*)d_in[9];
    const float* dU12 = (const float*)d_in[10];
    const float* b11 = (const float*)d_in[11];
    const float* b12 = (const float*)d_in[12];
    const float* W21 = (const float*)d_in[13];
    const float* W22 = (const float*)d_in[14];
    const float* U21 = (const float*)d_in[15];
    const float* U22 = (const float*)d_in[16];
    const float* dW21 = (const float*)d_in[17];
    const float* dW22 = (const float*)d_in[18];
    const float* dU21 = (const float*)d_in[19];
    const float* dU22 = (const float*)d_in[20];
    const float* b21 = (const float*)d_in[21];
    const float* b22 = (const float*)d_in[22];

    char* ws = (char*)d_ws;
    float* PT = (float*)ws;                                        // 2 MB
    float* mrec = (float*)(ws + (size_t)2 * 1024 * 1024);          // 2 MB
    unsigned int* flagb = (unsigned int*)(ws + (size_t)4 * 1024 * 1024);  // 16 KB
    float* out = (float*)d_out;

    hipMemsetAsync(flagb, 0, NB * NC * sizeof(unsigned int), stream);
    hipLaunchKernelGGL(precomp_kernel, dim3(NB * NS), dim3(64), 0, stream,
                       x, W12, dW12, PT);
    hipLaunchKernelGGL(lstm_rep_kernel, dim3(2 * NB), dim3(256), 0, stream,
                       PT, h0, c0,
                       W11, U11, dW11, dU11, U12, dU12, b11, b12,
                       W21, U21, dW21, dU21, W22, dW22, U22, dU22, b21, b22,
                       mrec, flagb, out);
}

// Round 12
// 414.025 us; speedup vs baseline: 4.4860x; 1.5337x over previous
//
#include <hip/hip_runtime.h>
#include <math.h>

#define NB 64       // batch
#define NS 512      // seq len
#define ND 512      // input dim
#define NH 512      // hidden
#define L2E 1.4426950408889634f

// 64-lane sum via DPP (VALU only). Total lands in lane 63.
__device__ __forceinline__ float dpp_sum64(float x) {
    x += __int_as_float(__builtin_amdgcn_update_dpp(0, __float_as_int(x), 0x111, 0xf, 0xf, true)); // row_shr:1
    x += __int_as_float(__builtin_amdgcn_update_dpp(0, __float_as_int(x), 0x112, 0xf, 0xf, true)); // row_shr:2
    x += __int_as_float(__builtin_amdgcn_update_dpp(0, __float_as_int(x), 0x114, 0xf, 0xf, true)); // row_shr:4
    x += __int_as_float(__builtin_amdgcn_update_dpp(0, __float_as_int(x), 0x118, 0xf, 0xf, true)); // row_shr:8
    x += __int_as_float(__builtin_amdgcn_update_dpp(0, __float_as_int(x), 0x142, 0xa, 0xf, true)); // row_bcast:15
    x += __int_as_float(__builtin_amdgcn_update_dpp(0, __float_as_int(x), 0x143, 0xc, 0xf, true)); // row_bcast:31
    return x;
}

__device__ __forceinline__ float bcast63(float x) {
    return __int_as_float(__builtin_amdgcn_readlane(__float_as_int(x), 63));
}
__device__ __forceinline__ float rcp_fast(float x) { return __builtin_amdgcn_rcpf(x); }
__device__ __forceinline__ float exp2_fast(float x) {
    float r;
    asm("v_exp_f32 %0, %1" : "=v"(r) : "v"(x));
    return r;
}
__device__ __forceinline__ void wg_barrier() {
    asm volatile("s_waitcnt lgkmcnt(0)\n\ts_barrier" ::: "memory");
}

// dot of an 8-float weight slice against the two h float4s
__device__ __forceinline__ float dot8s(const float* s, float4 x0, float4 x1) {
    float r = s[0] * x0.x;
    r = fmaf(s[1], x0.y, r); r = fmaf(s[2], x0.z, r); r = fmaf(s[3], x0.w, r);
    r = fmaf(s[4], x1.x, r); r = fmaf(s[5], x1.y, r); r = fmaf(s[6], x1.z, r);
    r = fmaf(s[7], x1.w, r);
    return r;
}

// permuted gather of factor row f (LDS slot s holds row 8*(s&63)+(s>>6))
#define LW(mat, f, arr)                                                       \
    {                                                                         \
        const float* M = (mat) + (f) * NH;                                    \
        arr[0] = M[kb];     arr[1] = M[kb + 8];                               \
        arr[2] = M[kb + 16]; arr[3] = M[kb + 24];                             \
        arr[4] = M[kb + 4]; arr[5] = M[kb + 12];                              \
        arr[6] = M[kb + 20]; arr[7] = M[kb + 28];                             \
    }

// one LSTM row update; coefficients cw/cdw/cu/cdu/bb pre-scaled by
// {-log2e, -log2e, +2log2e, -log2e}, so sigm(x)=1/(1+2^g), tanh=1-2/(1+2^g)
#define GATEX(t1, t2, m3, m4, bb, cS, hS)                                     \
    {                                                                         \
        float g0 = fmaf(cw[0], (t1), fmaf(cdw[0], (t2), fmaf(cu[0], (m3), fmaf(cdu[0], (m4), bb[0])))); \
        float g1 = fmaf(cw[1], (t1), fmaf(cdw[1], (t2), fmaf(cu[1], (m3), fmaf(cdu[1], (m4), bb[1])))); \
        float g2 = fmaf(cw[2], (t1), fmaf(cdw[2], (t2), fmaf(cu[2], (m3), fmaf(cdu[2], (m4), bb[2])))); \
        float g3 = fmaf(cw[3], (t1), fmaf(cdw[3], (t2), fmaf(cu[3], (m3), fmaf(cdu[3], (m4), bb[3])))); \
        float ig = rcp_fast(1.0f + exp2_fast(g0));                            \
        float fg = rcp_fast(1.0f + exp2_fast(g1));                            \
        float gg = fmaf(-2.0f, rcp_fast(1.0f + exp2_fast(g2)), 1.0f);         \
        float og = rcp_fast(1.0f + exp2_fast(g3));                            \
        cS = fmaf(fg, cS, ig * gg);                                           \
        hS = og * fmaf(-2.0f, rcp_fast(1.0f + exp2_fast(cS * (2.0f * L2E))), 1.0f); \
    }

// ---------------------------------------------------------------------------
// Kernel A: PT[bt][4g+{0,1,2,3}] = {W12x[g], W12x[g+4], dW12x[g], dW12x[g+4]}
// (wave-g-friendly layout: producer wave g reads ONE float4 per step)
// ---------------------------------------------------------------------------
__global__ __launch_bounds__(64) void precomp_kernel(
    const float* __restrict__ x, const float* __restrict__ W12,
    const float* __restrict__ dW12, float* __restrict__ PT) {
    int bt = blockIdx.x;
    int l = threadIdx.x;
    const float4* xr = (const float4*)(x + (size_t)bt * ND);
    float4 xv0 = xr[l];
    float4 xv1 = xr[64 + l];

    float acc[16];
#pragma unroll
    for (int f = 0; f < 8; ++f) {
        const float4* w = (const float4*)(W12 + f * ND);
        float4 a = w[l], b = w[64 + l];
        float s = a.x * xv0.x;
        s = fmaf(a.y, xv0.y, s); s = fmaf(a.z, xv0.z, s); s = fmaf(a.w, xv0.w, s);
        s = fmaf(b.x, xv1.x, s); s = fmaf(b.y, xv1.y, s); s = fmaf(b.z, xv1.z, s);
        s = fmaf(b.w, xv1.w, s);
        acc[f] = s;
        const float4* dw = (const float4*)(dW12 + f * ND);
        float4 c = dw[l], d = dw[64 + l];
        float u = c.x * xv0.x;
        u = fmaf(c.y, xv0.y, u); u = fmaf(c.z, xv0.z, u); u = fmaf(c.w, xv0.w, u);
        u = fmaf(d.x, xv1.x, u); u = fmaf(d.y, xv1.y, u); u = fmaf(d.z, xv1.z, u);
        u = fmaf(d.w, xv1.w, u);
        acc[8 + f] = u;
    }
#pragma unroll
    for (int f = 0; f < 16; ++f) acc[f] = dpp_sum64(acc[f]);

    if (l == 63) {
        float4* o = (float4*)(PT + (size_t)bt * 16);
#pragma unroll
        for (int g = 0; g < 4; ++g)
            o[g] = make_float4(acc[g], acc[g + 4], acc[8 + g], acc[12 + g]);
    }
}

// ---------------------------------------------------------------------------
// Kernel B: FUSED producer+consumer, one 8-wave block per batch element.
// Waves 0-3 (producer): layer-1 recurrence at step i + W22/dW22 projections
//   of h1(i) -> 16-float LDS handoff buffer mr[(i-1)&1].
// Waves 4-7 (consumer): layer-2 recurrence at step s=i-2, reading mr[s&1].
// Wave g owns factors {g, g+4} and rows {8l+g, 8l+g+4}: the m-values a
// row needs come from its OWN wave's reductions (readlane broadcast) —
// no cross-wave exchange for gates. ONE lgkm-only barrier per iteration.
// Producer and consumer waves share each SIMD -> mutual latency hiding.
// ---------------------------------------------------------------------------
__global__ __launch_bounds__(512, 2) void lstm_fused_kernel(
    const float* __restrict__ PT, const float* __restrict__ h0,
    const float* __restrict__ c0,
    const float* __restrict__ W11, const float* __restrict__ U11,
    const float* __restrict__ dW11, const float* __restrict__ dU11,
    const float* __restrict__ U12, const float* __restrict__ dU12,
    const float* __restrict__ b11, const float* __restrict__ b12,
    const float* __restrict__ W21, const float* __restrict__ U21,
    const float* __restrict__ dW21, const float* __restrict__ dU21,
    const float* __restrict__ W22, const float* __restrict__ dW22,
    const float* __restrict__ U22, const float* __restrict__ dU22,
    const float* __restrict__ b21, const float* __restrict__ b22,
    float* __restrict__ out) {
    int b = blockIdx.x;
    int tid = threadIdx.x;
    int wv = tid >> 6;
    int l = tid & 63;
    int g = wv & 3;                 // factor pair {g, g+4}
    int kb = 32 * (l & 15) + (l >> 4);
    int rA = 8 * l + g, rB = 8 * l + g + 4;   // owned rows

    __shared__ float Ps[NS * 16];   // 32 KB staged P slice
    __shared__ float hb1[2][NH];    // layer-1 h (permuted slots)
    __shared__ float hb2[2][NH];    // layer-2 h
    __shared__ float mr[2][16];     // L1->L2 projection handoff

    // stage P (all 8 waves)
    {
        const float4* src = (const float4*)(PT + (size_t)b * NS * 16);
        float4* dst = (float4*)Ps;
#pragma unroll
        for (int i = 0; i < 4; ++i) dst[tid + i * 512] = src[tid + i * 512];
    }

    float* hn = out + (size_t)NB * NS * NH;
    float* cn = hn + (size_t)2 * NB * NH;
    const float SQ[4] = {-L2E, -L2E, 2.0f * L2E, -L2E};

    if (wv < 4) {
        // ========================= PRODUCER (layer 1) ======================
        float wU0[8], wU1[8], wD0[8], wD1[8], wW0[8], wW1[8], wV0[8], wV1[8];
        LW(U12, g, wU0)      LW(U12, g + 4, wU1)
        LW(dU12, g, wD0)     LW(dU12, g + 4, wD1)
        LW(W22, g, wW0)      LW(W22, g + 4, wW1)
        LW(dW22, g, wV0)     LW(dW22, g + 4, wV1)

        float cw[4], cdw[4], cu[4], cdu[4], bbA[4], bbB[4];
#pragma unroll
        for (int q = 0; q < 4; ++q) {
            cw[q] = W11[q * 64 + l] * SQ[q];
            cdw[q] = dW11[q * 64 + l] * SQ[q];
            cu[q] = U11[q * 64 + l] * SQ[q];
            cdu[q] = dU11[q * 64 + l] * SQ[q];
            bbA[q] = (b11[q * NH + rA] + b12[q * NH + rA]) * SQ[q];
            bbB[q] = (b11[q * NH + rB] + b12[q * NH + rB]) * SQ[q];
        }
        float hA = h0[(size_t)b * NH + rA], hB = h0[(size_t)b * NH + rB];
        float cA = c0[(size_t)b * NH + rA], cB = c0[(size_t)b * NH + rB];
        hb1[0][64 * g + l] = hA;
        hb1[0][64 * (g + 4) + l] = hB;
        wg_barrier();

        for (int i = 0; i <= NS + 1; ++i) {
            if (i <= NS) {
                float4 x0 = *(const float4*)&hb1[i & 1][4 * l];
                float4 x1 = *(const float4*)&hb1[i & 1][256 + 4 * l];
                // projections of h1(i) -> mrec[i-1]
                float rWa = dpp_sum64(dot8s(wW0, x0, x1));
                float rWb = dpp_sum64(dot8s(wW1, x0, x1));
                float rVa = dpp_sum64(dot8s(wV0, x0, x1));
                float rVb = dpp_sum64(dot8s(wV1, x0, x1));
                if (i > 0 && l == 63)
                    *(float4*)&mr[(i - 1) & 1][4 * g] =
                        make_float4(rWa, rWb, rVa, rVb);
                if (i < NS) {
                    float rUa = dpp_sum64(dot8s(wU0, x0, x1));
                    float rUb = dpp_sum64(dot8s(wU1, x0, x1));
                    float rDa = dpp_sum64(dot8s(wD0, x0, x1));
                    float rDb = dpp_sum64(dot8s(wD1, x0, x1));
                    float m3A = bcast63(rUa), m3B = bcast63(rUb);
                    float m4A = bcast63(rDa), m4B = bcast63(rDb);
                    float4 pv = *(const float4*)&Ps[i * 16 + 4 * g];
                    GATEX(pv.x, pv.z, m3A, m4A, bbA, cA, hA)
                    GATEX(pv.y, pv.w, m3B, m4B, bbB, cB, hB)
                    hb1[(i + 1) & 1][64 * g + l] = hA;
                    hb1[(i + 1) & 1][64 * (g + 4) + l] = hB;
                }
            }
            wg_barrier();
        }
        hn[(size_t)b * NH + rA] = hA;
        hn[(size_t)b * NH + rB] = hB;
        cn[(size_t)b * NH + rA] = cA;
        cn[(size_t)b * NH + rB] = cB;
    } else {
        // ========================= CONSUMER (layer 2) ======================
        float wU0[8], wU1[8], wD0[8], wD1[8];
        LW(U22, g, wU0)      LW(U22, g + 4, wU1)
        LW(dU22, g, wD0)     LW(dU22, g + 4, wD1)

        float cw[4], cdw[4], cu[4], cdu[4], bbA[4], bbB[4];
#pragma unroll
        for (int q = 0; q < 4; ++q) {
            cw[q] = W21[q * 64 + l] * SQ[q];
            cdw[q] = dW21[q * 64 + l] * SQ[q];
            cu[q] = U21[q * 64 + l] * SQ[q];
            cdu[q] = dU21[q * 64 + l] * SQ[q];
            bbA[q] = (b21[q * NH + rA] + b22[q * NH + rA]) * SQ[q];
            bbB[q] = (b21[q * NH + rB] + b22[q * NH + rB]) * SQ[q];
        }
        const float* h0p = h0 + (size_t)NB * NH + (size_t)b * NH;
        const float* c0p = c0 + (size_t)NB * NH + (size_t)b * NH;
        float hA = h0p[rA], hB = h0p[rB];
        float cA = c0p[rA], cB = c0p[rB];
        hb2[0][64 * g + l] = hA;
        hb2[0][64 * (g + 4) + l] = hB;
        wg_barrier();

        float* outb = out + (size_t)b * NS * NH;
        for (int i = 0; i <= NS + 1; ++i) {
            int s = i - 2;
            if (s >= 0) {
                float4 y0 = *(const float4*)&hb2[s & 1][4 * l];
                float4 y1 = *(const float4*)&hb2[s & 1][256 + 4 * l];
                float rUa = dpp_sum64(dot8s(wU0, y0, y1));
                float rUb = dpp_sum64(dot8s(wU1, y0, y1));
                float rDa = dpp_sum64(dot8s(wD0, y0, y1));
                float rDb = dpp_sum64(dot8s(wD1, y0, y1));
                float m5A = bcast63(rUa), m5B = bcast63(rUb);
                float m6A = bcast63(rDa), m6B = bcast63(rDb);
                float4 mv = *(const float4*)&mr[s & 1][4 * g];
                GATEX(mv.x, mv.z, m5A, m6A, bbA, cA, hA)
                GATEX(mv.y, mv.w, m5B, m6B, bbB, cB, hB)
                hb2[(s + 1) & 1][64 * g + l] = hA;
                hb2[(s + 1) & 1][64 * (g + 4) + l] = hB;
                outb[(size_t)s * NH + rA] = hA;   // fire-and-forget
                outb[(size_t)s * NH + rB] = hB;
            }
            wg_barrier();
        }
        hn[(size_t)NB * NH + (size_t)b * NH + rA] = hA;
        hn[(size_t)NB * NH + (size_t)b * NH + rB] = hB;
        cn[(size_t)NB * NH + (size_t)b * NH + rA] = cA;
        cn[(size_t)NB * NH + (size_t)b * NH + rB] = cB;
    }
}

extern "C" void kernel_launch(void* const* d_in, const int* in_sizes, int n_in,
                              void* d_out, int out_size, void* d_ws, size_t ws_size,
                              hipStream_t stream) {
    const float* x = (const float*)d_in[0];
    const float* h0 = (const float*)d_in[1];
    const float* c0 = (const float*)d_in[2];
    const float* W11 = (const float*)d_in[3];
    const float* W12 = (const float*)d_in[4];
    const float* U11 = (const float*)d_in[5];
    const float* U12 = (const float*)d_in[6];
    const float* dW11 = (const float*)d_in[7];
    const float* dW12 = (const float*)d_in[8];
    const float* dU11 = (const float*)d_in[9];
    const float* dU12 = (const float*)d_in[10];
    const float* b11 = (const float*)d_in[11];
    const float* b12 = (const float*)d_in[12];
    const float* W21 = (const float*)d_in[13];
    const float* W22 = (const float*)d_in[14];
    const float* U21 = (const float*)d_in[15];
    const float* U22 = (const float*)d_in[16];
    const float* dW21 = (const float*)d_in[17];
    const float* dW22 = (const float*)d_in[18];
    const float* dU21 = (const float*)d_in[19];
    const float* dU22 = (const float*)d_in[20];
    const float* b21 = (const float*)d_in[21];
    const float* b22 = (const float*)d_in[22];

    float* PT = (float*)d_ws;   // 2 MB
    float* out = (float*)d_out;

    hipLaunchKernelGGL(precomp_kernel, dim3(NB * NS), dim3(64), 0, stream,
                       x, W12, dW12, PT);
    hipLaunchKernelGGL(lstm_fused_kernel, dim3(NB), dim3(512), 0, stream,
                       PT, h0, c0,
                       W11, U11, dW11, dU11, U12, dU12, b11, b12,
                       W21, U21, dW21, dU21, W22, dW22, U22, dU22, b21, b22,
                       out);
}